// Round 6
// baseline (315.164 us; speedup 1.0000x reference)
//
#include <hip/hip_runtime.h>
#include <cstdint>

typedef __attribute__((ext_vector_type(8))) short short8;
typedef __attribute__((ext_vector_type(4))) float f32x4;
typedef unsigned short u16t;

// ---------- helpers ----------
__device__ __forceinline__ u16t f2bf(float f) {
  uint32_t u = __float_as_uint(f);
  u += 0x7fffu + ((u >> 16) & 1u);   // RNE
  return (u16t)(u >> 16);
}

__device__ __forceinline__ uint32_t cvtpk(float lo, float hi) {
  uint32_t r;
  asm("v_cvt_pk_bf16_f32 %0, %1, %2" : "=v"(r) : "v"(lo), "v"(hi));
  return r;
}

__device__ __forceinline__ void gload_lds16(const void* g, void* l) {
  __builtin_amdgcn_global_load_lds(
      (const __attribute__((address_space(1))) void*)g,
      (__attribute__((address_space(3))) void*)l, 16, 0, 0);
}

// ---------- f32 -> bf16 convert ----------
__global__ __launch_bounds__(256) void cvt_bf16_kernel(const float* __restrict__ in,
                                                       u16t* __restrict__ out, int n8) {
  int i = blockIdx.x * 256 + threadIdx.x;
  if (i >= n8) return;
  const float4* p = (const float4*)in + (size_t)i * 2;
  float4 a = p[0], b = p[1];
  union { short8 v; u16t e[8]; } r;
  r.e[0] = f2bf(a.x); r.e[1] = f2bf(a.y); r.e[2] = f2bf(a.z); r.e[3] = f2bf(a.w);
  r.e[4] = f2bf(b.x); r.e[5] = f2bf(b.y); r.e[6] = f2bf(b.z); r.e[7] = f2bf(b.w);
  *((short8*)out + i) = r.v;
}

// ---------- LayerNorm (row = 768 f32) -> bf16 ----------
__global__ __launch_bounds__(256) void ln_kernel(const float* __restrict__ x,
                                                 const float* __restrict__ g,
                                                 const float* __restrict__ b,
                                                 u16t* __restrict__ out) {
  int row = blockIdx.x, tid = threadIdx.x;
  int wave = tid >> 6, lane = tid & 63;
  const float* xr = x + (size_t)row * 768;
  float v0 = xr[tid], v1 = xr[tid + 256], v2 = xr[tid + 512];
  float s = v0 + v1 + v2;
  float q = v0 * v0 + v1 * v1 + v2 * v2;
#pragma unroll
  for (int m = 32; m >= 1; m >>= 1) {
    s += __shfl_xor(s, m, 64);
    q += __shfl_xor(q, m, 64);
  }
  __shared__ float red[8];
  if (lane == 0) { red[wave] = s; red[4 + wave] = q; }
  __syncthreads();
  s = red[0] + red[1] + red[2] + red[3];
  q = red[4] + red[5] + red[6] + red[7];
  float mu = s * (1.0f / 768.0f);
  float var = q * (1.0f / 768.0f) - mu * mu;
  float rs = rsqrtf(var + 1e-5f);
  u16t* orow = out + (size_t)row * 768;
  orow[tid]       = f2bf((v0 - mu) * rs * g[tid]       + b[tid]);
  orow[tid + 256] = f2bf((v1 - mu) * rs * g[tid + 256] + b[tid + 256]);
  orow[tid + 512] = f2bf((v2 - mu) * rs * g[tid + 512] + b[tid + 512]);
}

// ---------- 8-wave deep-pipelined GEMM: C[M,N] = A[M,K] @ W[N,K]^T ----------
// Tile 128(M) x 256(N), BK=64, 512 threads = 8 waves (2M x 4N), per-wave 64x64.
// LDS 96KB (2-buf), wave-aligned staging, quad = 2 phases (kh), counted-free
// vmcnt(0) at quad end with ~2-phase lead. Swapped MFMA operands so each lane
// owns 4 consecutive output columns -> packed stores.
// EPI 0: bf16 store; EPI 1: f32 store of acc+bias+res; EPI 2: bf16 gelu(acc+bias)
template <int EPI>
__global__ __launch_bounds__(512, 1) void gemm8(const u16t* __restrict__ A,
                                                const u16t* __restrict__ W,
                                                void* __restrict__ Cout,
                                                const float* __restrict__ bias,
                                                const float* __restrict__ res,
                                                int N, int K, int nbn) {
  __shared__ __align__(16) u16t As[2][128 * 64];
  __shared__ __align__(16) u16t Bs[2][256 * 64];
  int tid = threadIdx.x;
  int wid = tid >> 6, lane = tid & 63;
  int wr = wid >> 2, wc = wid & 3;
  int q = lane & 15, g = lane >> 4;

  // XCD-aware swizzle (grid % 8 == 0 for all our launches)
  int nwg = gridDim.x;
  int bid = blockIdx.x;
  int swz = (bid & 7) * (nwg >> 3) + (bid >> 3);
  int bmi = swz / nbn, bni = swz % nbn;
  int bm = bmi * 128, bn = bni * 256;

  // staging sources (pre-swizzled slot; 8-row chunks of 1KB)
  int lr = lane >> 3, lc = lane & 7;
  const u16t* Asrc = A + (size_t)(bm + lr) * K + ((lc ^ lr) * 8);
  const u16t* Wsrc = W + (size_t)(bn + lr) * K + ((lc ^ lr) * 8);

  // wave-aligned chunk assignment:
  // A-half wr (chunks wr*8..wr*8+7) staged by waves with this wr (4 waves x 2)
  int gi = wid & 3;
  int ca0 = wr * 8 + gi * 2;
  // B-half wc>>1 (chunks h*16..h*16+15) staged by waves with this half (4 x 4)
  int hB = wc >> 1;
  int gj = (wid & 1) | ((wid >> 2) << 1);
  int cb0 = hB * 16 + gj * 4;

  f32x4 acc[4][4] = {};

  auto stage = [&](int kt, int db) {
    gload_lds16(Asrc + (size_t)(ca0 * 8) * K + kt, (void*)(As[db] + ca0 * 512));
    gload_lds16(Asrc + (size_t)(ca0 * 8 + 8) * K + kt, (void*)(As[db] + ca0 * 512 + 512));
#pragma unroll
    for (int j = 0; j < 4; j++)
      gload_lds16(Wsrc + (size_t)((cb0 + j) * 8) * K + kt, (void*)(Bs[db] + (cb0 + j) * 512));
  };

  // prologue: quad 0 into buf 0
  stage(0, 0);
  __syncthreads();

  int NT = K >> 6;
  for (int T = 0; T < NT; ++T) {
    int db = T & 1;
    if (T + 1 < NT) stage((T + 1) * 64, db ^ 1);   // ~2-phase lead before the wait
    const u16t* Ab = As[db];
    const u16t* Bb = Bs[db];
#pragma unroll
    for (int kh = 0; kh < 2; kh++) {
      short8 af[4], bf[4];
#pragma unroll
      for (int x = 0; x < 4; x++) {
        int slot = ((kh * 4 + g) ^ (q & 7)) * 8;
        af[x] = *(const short8*)(Ab + (wr * 64 + x * 16 + q) * 64 + slot);
        bf[x] = *(const short8*)(Bb + (wc * 64 + x * 16 + q) * 64 + slot);
      }
      __builtin_amdgcn_s_barrier();
      __builtin_amdgcn_s_setprio(1);
#pragma unroll
      for (int mf = 0; mf < 4; mf++)
#pragma unroll
        for (int nf = 0; nf < 4; nf++)
          acc[mf][nf] = __builtin_amdgcn_mfma_f32_16x16x32_bf16(bf[nf], af[mf], acc[mf][nf], 0, 0, 0);
      __builtin_amdgcn_s_setprio(0);
      if (kh == 1) asm volatile("s_waitcnt vmcnt(0)" ::: "memory");
      __builtin_amdgcn_s_barrier();
    }
  }

  // epilogue: lane holds m = ...+q (fixed row), n = ...+g*4+i (4 consecutive cols)
#pragma unroll
  for (int mf = 0; mf < 4; mf++) {
    int m = bm + wr * 64 + mf * 16 + q;
#pragma unroll
    for (int nf = 0; nf < 4; nf++) {
      int n = bn + wc * 64 + nf * 16 + g * 4;
      f32x4 v = acc[mf][nf];
      if constexpr (EPI == 0) {
        uint2 pk = make_uint2(cvtpk(v[0], v[1]), cvtpk(v[2], v[3]));
        *(uint2*)((u16t*)Cout + (size_t)m * N + n) = pk;
      } else if constexpr (EPI == 1) {
        const float4 bv = *(const float4*)(bias + n);
        const float4 rv = *(const float4*)(res + (size_t)m * N + n);
        float4 o;
        o.x = v[0] + bv.x + rv.x; o.y = v[1] + bv.y + rv.y;
        o.z = v[2] + bv.z + rv.z; o.w = v[3] + bv.w + rv.w;
        *(float4*)((float*)Cout + (size_t)m * N + n) = o;
      } else {
        const float4 bv = *(const float4*)(bias + n);
        float t0 = v[0] + bv.x, t1 = v[1] + bv.y, t2 = v[2] + bv.z, t3 = v[3] + bv.w;
        t0 = 0.5f * t0 * (1.0f + erff(t0 * 0.70710678118f));
        t1 = 0.5f * t1 * (1.0f + erff(t1 * 0.70710678118f));
        t2 = 0.5f * t2 * (1.0f + erff(t2 * 0.70710678118f));
        t3 = 0.5f * t3 * (1.0f + erff(t3 * 0.70710678118f));
        uint2 pk = make_uint2(cvtpk(t0, t1), cvtpk(t2, t3));
        *(uint2*)((u16t*)Cout + (size_t)m * N + n) = pk;
      }
    }
  }
}

// ---------- V transpose: qkvb V-part -> vt[head][64][1024] ----------
__global__ __launch_bounds__(256) void vtrans_kernel(const u16t* __restrict__ qkv,
                                                     u16t* __restrict__ vt) {
  __shared__ u16t T[64][66];
  int h = blockIdx.x % 12, bb = blockIdx.x / 12, kt = blockIdx.y * 64;
  int t = threadIdx.x;
  int r = t >> 2, dc = t & 3;
  const u16t* src = qkv + (size_t)(bb * 1024 + kt + r) * 2304 + 1536 + h * 64 + dc * 16;
  union { uint4 u[2]; u16t e[16]; uint32_t w[8]; } buf;
  buf.u[0] = *(const uint4*)src;
  buf.u[1] = *(const uint4*)(src + 8);
#pragma unroll
  for (int j = 0; j < 8; j++)
    *(uint32_t*)&T[r][dc * 16 + 2 * j] = buf.w[j];
  __syncthreads();
  int d = t >> 2, kc = t & 3;
  union { uint4 u[2]; u16t e[16]; } o;
#pragma unroll
  for (int j = 0; j < 16; j++) o.e[j] = T[kc * 16 + j][d];
  u16t* dst = vt + ((size_t)blockIdx.x * 64 + d) * 1024 + kt + kc * 16;
  *(uint4*)dst = o.u[0];
  *(uint4*)(dst + 8) = o.u[1];
}

// ---------- flash attention: block-shared LDS staging + 2-phase pipeline ----------
__global__ __launch_bounds__(256, 3) void attn_kernel(const u16t* __restrict__ qkv,
                                                      const u16t* __restrict__ vt,
                                                      u16t* __restrict__ ctx) {
  __shared__ __align__(16) u16t Ks[2][64 * 64];
  __shared__ __align__(16) u16t Vs[2][64 * 64];
  __shared__ __align__(16) u16t Plds[4][32 * 72];
  int tid = threadIdx.x;
  int wave = tid >> 6, lane = tid & 63;
  int q = lane & 15, g = lane >> 4;

  int bid = blockIdx.x;
  int xcd = bid & 7, j = bid >> 3;
  int head = xcd + 8 * (j >> 3);
  int qt = (j & 7) * 128 + wave * 32;
  int b = head / 12, h = head % 12;

  const u16t* base = qkv + (size_t)b * 1024 * 2304 + h * 64;
  const u16t* kbase = base + 768;
  const u16t* vtb = vt + (size_t)head * 64 * 1024;

  short8 qf[2][2];
#pragma unroll
  for (int hf = 0; hf < 2; hf++)
#pragma unroll
    for (int hh = 0; hh < 2; hh++)
      qf[hf][hh] = *(const short8*)(base + (size_t)(qt + hf * 16 + q) * 2304 + hh * 32 + g * 8);

  int lr = lane >> 3, lc = lane & 7;
  const u16t* ksrc = kbase + (size_t)lr * 2304 + (size_t)((lc ^ lr) * 8);
  const u16t* vsrc = vtb + (size_t)lr * 1024 + (size_t)((lc ^ lr) * 8);
  int c0 = wave * 2, c1 = wave * 2 + 1;

  auto stage = [&](int kt, int buf) {
    gload_lds16(ksrc + (size_t)(kt + c0 * 8) * 2304, (void*)(Ks[buf] + c0 * 512));
    gload_lds16(ksrc + (size_t)(kt + c1 * 8) * 2304, (void*)(Ks[buf] + c1 * 512));
    gload_lds16(vsrc + (size_t)(c0 * 8) * 1024 + kt, (void*)(Vs[buf] + c0 * 512));
    gload_lds16(vsrc + (size_t)(c1 * 8) * 1024 + kt, (void*)(Vs[buf] + c1 * 512));
  };

  float mA = -1e30f, mB = -1e30f, lA = 0.f, lB = 0.f;
  f32x4 oA[4] = {}, oB[4] = {};
  u16t* Pw = Plds[wave];

  stage(0, 0);
  __syncthreads();

  for (int t = 0; t < 16; ++t) {
    int buf = t & 1;
    if (t < 15) stage((t + 1) * 64, buf ^ 1);

    const u16t* Kb = Ks[buf];
    const u16t* Vb = Vs[buf];

    f32x4 sA[4] = {}, sB[4] = {};
    __builtin_amdgcn_s_setprio(1);
#pragma unroll
    for (int n = 0; n < 4; n++) {
      int row = n * 16 + q;
      short8 k0 = *(const short8*)(Kb + row * 64 + ((g ^ (q & 7)) * 8));
      short8 k1 = *(const short8*)(Kb + row * 64 + (((4 + g) ^ (q & 7)) * 8));
      sA[n] = __builtin_amdgcn_mfma_f32_16x16x32_bf16(k0, qf[0][0], sA[n], 0, 0, 0);
      sA[n] = __builtin_amdgcn_mfma_f32_16x16x32_bf16(k1, qf[0][1], sA[n], 0, 0, 0);
      sB[n] = __builtin_amdgcn_mfma_f32_16x16x32_bf16(k0, qf[1][0], sB[n], 0, 0, 0);
      sB[n] = __builtin_amdgcn_mfma_f32_16x16x32_bf16(k1, qf[1][1], sB[n], 0, 0, 0);
    }
    __builtin_amdgcn_s_setprio(0);

    float alphaA, alphaB;
    {
      float t0 = fmaxf(fmaxf(sA[0][0], sA[0][1]), fmaxf(sA[0][2], sA[0][3]));
      float t1 = fmaxf(fmaxf(sA[1][0], sA[1][1]), fmaxf(sA[1][2], sA[1][3]));
      float t2 = fmaxf(fmaxf(sA[2][0], sA[2][1]), fmaxf(sA[2][2], sA[2][3]));
      float t3 = fmaxf(fmaxf(sA[3][0], sA[3][1]), fmaxf(sA[3][2], sA[3][3]));
      float tm = fmaxf(fmaxf(t0, t1), fmaxf(t2, t3));
      tm = fmaxf(tm, __shfl_xor(tm, 16, 64));
      tm = fmaxf(tm, __shfl_xor(tm, 32, 64));
      float mnew = fmaxf(mA, tm);
      alphaA = __expf((mA - mnew) * 0.125f);
      mA = mnew;
#pragma unroll
      for (int n = 0; n < 4; n++)
#pragma unroll
        for (int i = 0; i < 4; i++) sA[n][i] = __expf((sA[n][i] - mnew) * 0.125f);
      float r0 = (sA[0][0] + sA[0][1]) + (sA[0][2] + sA[0][3]);
      float r1 = (sA[1][0] + sA[1][1]) + (sA[1][2] + sA[1][3]);
      float r2 = (sA[2][0] + sA[2][1]) + (sA[2][2] + sA[2][3]);
      float r3 = (sA[3][0] + sA[3][1]) + (sA[3][2] + sA[3][3]);
      float rs = (r0 + r1) + (r2 + r3);
      rs += __shfl_xor(rs, 16, 64);
      rs += __shfl_xor(rs, 32, 64);
      lA = lA * alphaA + rs;
#pragma unroll
      for (int n = 0; n < 4; n++) {
        uint32_t w0 = cvtpk(sA[n][0], sA[n][1]);
        uint32_t w1 = cvtpk(sA[n][2], sA[n][3]);
        *(uint2*)(Pw + q * 72 + n * 16 + g * 4) = make_uint2(w0, w1);
      }
    }
    {
      float t0 = fmaxf(fmaxf(sB[0][0], sB[0][1]), fmaxf(sB[0][2], sB[0][3]));
      float t1 = fmaxf(fmaxf(sB[1][0], sB[1][1]), fmaxf(sB[1][2], sB[1][3]));
      float t2 = fmaxf(fmaxf(sB[2][0], sB[2][1]), fmaxf(sB[2][2], sB[2][3]));
      float t3 = fmaxf(fmaxf(sB[3][0], sB[3][1]), fmaxf(sB[3][2], sB[3][3]));
      float tm = fmaxf(fmaxf(t0, t1), fmaxf(t2, t3));
      tm = fmaxf(tm, __shfl_xor(tm, 16, 64));
      tm = fmaxf(tm, __shfl_xor(tm, 32, 64));
      float mnew = fmaxf(mB, tm);
      alphaB = __expf((mB - mnew) * 0.125f);
      mB = mnew;
#pragma unroll
      for (int n = 0; n < 4; n++)
#pragma unroll
        for (int i = 0; i < 4; i++) sB[n][i] = __expf((sB[n][i] - mnew) * 0.125f);
      float r0 = (sB[0][0] + sB[0][1]) + (sB[0][2] + sB[0][3]);
      float r1 = (sB[1][0] + sB[1][1]) + (sB[1][2] + sB[1][3]);
      float r2 = (sB[2][0] + sB[2][1]) + (sB[2][2] + sB[2][3]);
      float r3 = (sB[3][0] + sB[3][1]) + (sB[3][2] + sB[3][3]);
      float rs = (r0 + r1) + (r2 + r3);
      rs += __shfl_xor(rs, 16, 64);
      rs += __shfl_xor(rs, 32, 64);
      lB = lB * alphaB + rs;
#pragma unroll
      for (int n = 0; n < 4; n++) {
        uint32_t w0 = cvtpk(sB[n][0], sB[n][1]);
        uint32_t w1 = cvtpk(sB[n][2], sB[n][3]);
        *(uint2*)(Pw + (16 + q) * 72 + n * 16 + g * 4) = make_uint2(w0, w1);
      }
    }

#pragma unroll
    for (int n = 0; n < 4; n++)
#pragma unroll
      for (int i = 0; i < 4; i++) {
        oA[n][i] *= alphaA;
        oB[n][i] *= alphaB;
      }

    short8 pA[2], pB[2];
#pragma unroll
    for (int hh = 0; hh < 2; hh++) {
      pA[hh] = *(const short8*)(Pw + q * 72 + hh * 32 + g * 8);
      pB[hh] = *(const short8*)(Pw + (16 + q) * 72 + hh * 32 + g * 8);
    }
    __builtin_amdgcn_s_setprio(1);
#pragma unroll
    for (int n = 0; n < 4; n++) {
      int row = n * 16 + q;
      short8 v0 = *(const short8*)(Vb + row * 64 + ((g ^ (q & 7)) * 8));
      short8 v1 = *(const short8*)(Vb + row * 64 + (((4 + g) ^ (q & 7)) * 8));
      oA[n] = __builtin_amdgcn_mfma_f32_16x16x32_bf16(v0, pA[0], oA[n], 0, 0, 0);
      oA[n] = __builtin_amdgcn_mfma_f32_16x16x32_bf16(v1, pA[1], oA[n], 0, 0, 0);
      oB[n] = __builtin_amdgcn_mfma_f32_16x16x32_bf16(v0, pB[0], oB[n], 0, 0, 0);
      oB[n] = __builtin_amdgcn_mfma_f32_16x16x32_bf16(v1, pB[1], oB[n], 0, 0, 0);
    }
    __builtin_amdgcn_s_setprio(0);

    __syncthreads();
  }

  float invA = 1.f / lA, invB = 1.f / lB;
  u16t* crowA = ctx + (size_t)(b * 1024 + qt + q) * 768 + h * 64;
  u16t* crowB = ctx + (size_t)(b * 1024 + qt + 16 + q) * 768 + h * 64;
#pragma unroll
  for (int n = 0; n < 4; n++) {
    uint32_t a0 = (uint32_t)f2bf(oA[n][0] * invA) | ((uint32_t)f2bf(oA[n][1] * invA) << 16);
    uint32_t a1 = (uint32_t)f2bf(oA[n][2] * invA) | ((uint32_t)f2bf(oA[n][3] * invA) << 16);
    *(uint32_t*)(crowA + n * 16 + g * 4) = a0;
    *(uint32_t*)(crowA + n * 16 + g * 4 + 2) = a1;
    uint32_t b0 = (uint32_t)f2bf(oB[n][0] * invB) | ((uint32_t)f2bf(oB[n][1] * invB) << 16);
    uint32_t b1 = (uint32_t)f2bf(oB[n][2] * invB) | ((uint32_t)f2bf(oB[n][3] * invB) << 16);
    *(uint32_t*)(crowB + n * 16 + g * 4) = b0;
    *(uint32_t*)(crowB + n * 16 + g * 4 + 2) = b1;
  }
}

// ---------- launch ----------
extern "C" void kernel_launch(void* const* d_in, const int* in_sizes, int n_in,
                              void* d_out, int out_size, void* d_ws, size_t ws_size,
                              hipStream_t stream) {
  const float* x      = (const float*)d_in[0];
  const float* ln1_g  = (const float*)d_in[1];
  const float* ln1_b  = (const float*)d_in[2];
  const float* qkv_w  = (const float*)d_in[3];
  const float* proj_w = (const float*)d_in[4];
  const float* proj_b = (const float*)d_in[5];
  const float* ln2_g  = (const float*)d_in[6];
  const float* ln2_b  = (const float*)d_in[7];
  const float* fc1_w  = (const float*)d_in[8];
  const float* fc1_b  = (const float*)d_in[9];
  const float* fc2_w  = (const float*)d_in[10];
  const float* fc2_b  = (const float*)d_in[11];

  char* ws = (char*)d_ws;
  u16t* h1   = (u16t*)(ws + 0);           // 8192x768 bf16 (ln1 out; REUSED as vt; then ln2 out)
  u16t* qkvb = (u16t*)(ws + 12582912);    // 8192x2304 bf16
  u16t* ctx  = (u16t*)(ws + 50331648);    // 8192x768 bf16
  float* x2  = (float*)(ws + 62914560);   // 8192x768 f32
  u16t* hid  = (u16t*)(ws + 88080384);    // 8192x3072 bf16
  u16t* wq   = (u16t*)(ws + 138412032);   // 2304x768 bf16
  u16t* wp   = (u16t*)(ws + 141950976);   // 768x768 bf16
  u16t* w1   = (u16t*)(ws + 143130624);   // 3072x768 bf16
  u16t* w2   = (u16t*)(ws + 147849216);   // 768x3072 bf16
  u16t* vtb  = h1;                        // 96x64x1024 bf16, lifetime-disjoint
  float* out = (float*)d_out;

  cvt_bf16_kernel<<<864, 256, 0, stream>>>(qkv_w, wq, 221184);
  cvt_bf16_kernel<<<288, 256, 0, stream>>>(proj_w, wp, 73728);
  cvt_bf16_kernel<<<1152, 256, 0, stream>>>(fc1_w, w1, 294912);
  cvt_bf16_kernel<<<1152, 256, 0, stream>>>(fc2_w, w2, 294912);

  ln_kernel<<<8192, 256, 0, stream>>>(x, ln1_g, ln1_b, h1);
  gemm8<0><<<576, 512, 0, stream>>>(h1, wq, qkvb, nullptr, nullptr, 2304, 768, 9);
  vtrans_kernel<<<dim3(96, 16), 256, 0, stream>>>(qkvb, vtb);
  attn_kernel<<<768, 256, 0, stream>>>(qkvb, vtb, ctx);
  gemm8<1><<<192, 512, 0, stream>>>(ctx, wp, x2, proj_b, x, 768, 768, 3);
  ln_kernel<<<8192, 256, 0, stream>>>(x2, ln2_g, ln2_b, h1);
  gemm8<2><<<768, 512, 0, stream>>>(h1, w1, hid, fc1_b, nullptr, 3072, 768, 12);
  gemm8<1><<<192, 512, 0, stream>>>(hid, w2, out, fc2_b, x2, 768, 3072, 3);
}

// Round 7
// 287.420 us; speedup vs baseline: 1.0965x; 1.0965x over previous
//
#include <hip/hip_runtime.h>
#include <cstdint>

typedef __attribute__((ext_vector_type(8))) short short8;
typedef __attribute__((ext_vector_type(4))) float f32x4;
typedef unsigned short u16t;

// ---------- helpers ----------
__device__ __forceinline__ u16t f2bf(float f) {
  uint32_t u = __float_as_uint(f);
  u += 0x7fffu + ((u >> 16) & 1u);   // RNE
  return (u16t)(u >> 16);
}

__device__ __forceinline__ uint32_t cvtpk(float lo, float hi) {
  uint32_t r;
  asm("v_cvt_pk_bf16_f32 %0, %1, %2" : "=v"(r) : "v"(lo), "v"(hi));
  return r;
}

__device__ __forceinline__ void gload_lds16(const void* g, void* l) {
  __builtin_amdgcn_global_load_lds(
      (const __attribute__((address_space(1))) void*)g,
      (__attribute__((address_space(3))) void*)l, 16, 0, 0);
}

// ---------- f32 -> bf16 convert ----------
__global__ __launch_bounds__(256) void cvt_bf16_kernel(const float* __restrict__ in,
                                                       u16t* __restrict__ out, int n8) {
  int i = blockIdx.x * 256 + threadIdx.x;
  if (i >= n8) return;
  const float4* p = (const float4*)in + (size_t)i * 2;
  float4 a = p[0], b = p[1];
  union { short8 v; u16t e[8]; } r;
  r.e[0] = f2bf(a.x); r.e[1] = f2bf(a.y); r.e[2] = f2bf(a.z); r.e[3] = f2bf(a.w);
  r.e[4] = f2bf(b.x); r.e[5] = f2bf(b.y); r.e[6] = f2bf(b.z); r.e[7] = f2bf(b.w);
  *((short8*)out + i) = r.v;
}

// ---------- LayerNorm (row = 768 f32) -> bf16 ----------
__global__ __launch_bounds__(256) void ln_kernel(const float* __restrict__ x,
                                                 const float* __restrict__ g,
                                                 const float* __restrict__ b,
                                                 u16t* __restrict__ out) {
  int row = blockIdx.x, tid = threadIdx.x;
  int wave = tid >> 6, lane = tid & 63;
  const float* xr = x + (size_t)row * 768;
  float v0 = xr[tid], v1 = xr[tid + 256], v2 = xr[tid + 512];
  float s = v0 + v1 + v2;
  float q = v0 * v0 + v1 * v1 + v2 * v2;
#pragma unroll
  for (int m = 32; m >= 1; m >>= 1) {
    s += __shfl_xor(s, m, 64);
    q += __shfl_xor(q, m, 64);
  }
  __shared__ float red[8];
  if (lane == 0) { red[wave] = s; red[4 + wave] = q; }
  __syncthreads();
  s = red[0] + red[1] + red[2] + red[3];
  q = red[4] + red[5] + red[6] + red[7];
  float mu = s * (1.0f / 768.0f);
  float var = q * (1.0f / 768.0f) - mu * mu;
  float rs = rsqrtf(var + 1e-5f);
  u16t* orow = out + (size_t)row * 768;
  orow[tid]       = f2bf((v0 - mu) * rs * g[tid]       + b[tid]);
  orow[tid + 256] = f2bf((v1 - mu) * rs * g[tid + 256] + b[tid + 256]);
  orow[tid + 512] = f2bf((v2 - mu) * rs * g[tid + 512] + b[tid + 512]);
}

// ---------- GEMM: C[M,N] = A[M,K] @ W[N,K]^T  (bf16 in, fp32 acc) ----------
// Double-buffered LDS; stage(t+1) issued BEFORE compute(t); ONE barrier/K-step,
// so the vmcnt(0) drain at the barrier lands a full compute-phase after issue.
// Swapped MFMA operands: lane owns row m (fixed) x 4 consecutive cols -> packed stores.
// EPI 0: bf16 store; EPI 1: f32 store acc+bias+res; EPI 2: bf16 gelu(acc+bias)
template <int EPI, int BM, int MINB>
__global__ __launch_bounds__(256, MINB) void gemm_bt(const u16t* __restrict__ A,
                                                     const u16t* __restrict__ W,
                                                     void* __restrict__ Cout,
                                                     const float* __restrict__ bias,
                                                     const float* __restrict__ res,
                                                     int M, int N, int K) {
  __shared__ __align__(16) u16t As[2][BM * 64];
  __shared__ __align__(16) u16t Bs[2][128 * 64];
  constexpr int MF = BM / 32;
  int tid = threadIdx.x;
  int wave = tid >> 6, lane = tid & 63;
  int wr = wave >> 1, wc = wave & 1;
  int q = lane & 15, g = lane >> 4;
  int bm = blockIdx.y * BM;
  int bn = blockIdx.x * 128;
  f32x4 acc[MF][4] = {};

  int lr = lane >> 3, lc = lane & 7;
  const u16t* Abase = A + (size_t)(bm + lr) * K + ((lc ^ lr) * 8);
  const u16t* Wbase = W + (size_t)(bn + lr) * K + ((lc ^ lr) * 8);

  auto stage = [&](int kt, int db) {
#pragma unroll
    for (int i = 0; i < BM / 32; i++) {
      int chunk = wave * (BM / 32) + i;
      gload_lds16(Abase + (size_t)(chunk * 8) * K + kt, (void*)(As[db] + chunk * 512));
    }
#pragma unroll
    for (int i = 0; i < 4; i++) {
      int chunk = wave * 4 + i;
      gload_lds16(Wbase + (size_t)(chunk * 8) * K + kt, (void*)(Bs[db] + chunk * 512));
    }
  };

  stage(0, 0);
  __syncthreads();

  int NT = K >> 6;
  for (int t = 0; t < NT; ++t) {
    int db = t & 1;
    if (t + 1 < NT) stage((t + 1) * 64, db ^ 1);   // prefetch into other buffer
    const u16t* Ab = As[db];
    const u16t* Bb = Bs[db];

    short8 af[MF][2], bfr[4][2];
#pragma unroll
    for (int m = 0; m < MF; m++) {
      int row = wr * (BM / 2) + m * 16 + q;
#pragma unroll
      for (int s = 0; s < 2; s++)
        af[m][s] = *(const short8*)(Ab + row * 64 + (((s * 4 + g) ^ (row & 7)) * 8));
    }
#pragma unroll
    for (int n = 0; n < 4; n++) {
      int row = wc * 64 + n * 16 + q;
#pragma unroll
      for (int s = 0; s < 2; s++)
        bfr[n][s] = *(const short8*)(Bb + row * 64 + (((s * 4 + g) ^ (row & 7)) * 8));
    }
    __builtin_amdgcn_s_setprio(1);
#pragma unroll
    for (int m = 0; m < MF; m++)
#pragma unroll
      for (int n = 0; n < 4; n++) {
        acc[m][n] = __builtin_amdgcn_mfma_f32_16x16x32_bf16(bfr[n][0], af[m][0], acc[m][n], 0, 0, 0);
        acc[m][n] = __builtin_amdgcn_mfma_f32_16x16x32_bf16(bfr[n][1], af[m][1], acc[m][n], 0, 0, 0);
      }
    __builtin_amdgcn_s_setprio(0);
    __syncthreads();   // drains prefetch (issued a full compute-phase ago) + publishes buffer
  }

  // epilogue: lane holds row m = ...+q, cols n = ...+g*4+i (4 consecutive)
#pragma unroll
  for (int m = 0; m < MF; m++) {
    int r = bm + wr * (BM / 2) + m * 16 + q;
#pragma unroll
    for (int n = 0; n < 4; n++) {
      int c = bn + wc * 64 + n * 16 + g * 4;
      f32x4 v = acc[m][n];
      if constexpr (EPI == 0) {
        uint2 pk = make_uint2(cvtpk(v[0], v[1]), cvtpk(v[2], v[3]));
        *(uint2*)((u16t*)Cout + (size_t)r * N + c) = pk;
      } else if constexpr (EPI == 1) {
        const float4 bv = *(const float4*)(bias + c);
        const float4 rv = *(const float4*)(res + (size_t)r * N + c);
        float4 o;
        o.x = v[0] + bv.x + rv.x; o.y = v[1] + bv.y + rv.y;
        o.z = v[2] + bv.z + rv.z; o.w = v[3] + bv.w + rv.w;
        *(float4*)((float*)Cout + (size_t)r * N + c) = o;
      } else {
        const float4 bv = *(const float4*)(bias + c);
        float t0 = v[0] + bv.x, t1 = v[1] + bv.y, t2 = v[2] + bv.z, t3 = v[3] + bv.w;
        t0 = 0.5f * t0 * (1.0f + erff(t0 * 0.70710678118f));
        t1 = 0.5f * t1 * (1.0f + erff(t1 * 0.70710678118f));
        t2 = 0.5f * t2 * (1.0f + erff(t2 * 0.70710678118f));
        t3 = 0.5f * t3 * (1.0f + erff(t3 * 0.70710678118f));
        uint2 pk = make_uint2(cvtpk(t0, t1), cvtpk(t2, t3));
        *(uint2*)((u16t*)Cout + (size_t)r * N + c) = pk;
      }
    }
  }
}

// ---------- V transpose: qkvb V-part -> vt[head][64][1024] ----------
__global__ __launch_bounds__(256) void vtrans_kernel(const u16t* __restrict__ qkv,
                                                     u16t* __restrict__ vt) {
  __shared__ u16t T[64][66];
  int h = blockIdx.x % 12, bb = blockIdx.x / 12, kt = blockIdx.y * 64;
  int t = threadIdx.x;
  int r = t >> 2, dc = t & 3;
  const u16t* src = qkv + (size_t)(bb * 1024 + kt + r) * 2304 + 1536 + h * 64 + dc * 16;
  union { uint4 u[2]; u16t e[16]; uint32_t w[8]; } buf;
  buf.u[0] = *(const uint4*)src;
  buf.u[1] = *(const uint4*)(src + 8);
#pragma unroll
  for (int j = 0; j < 8; j++)
    *(uint32_t*)&T[r][dc * 16 + 2 * j] = buf.w[j];
  __syncthreads();
  int d = t >> 2, kc = t & 3;
  union { uint4 u[2]; u16t e[16]; } o;
#pragma unroll
  for (int j = 0; j < 16; j++) o.e[j] = T[kc * 16 + j][d];
  u16t* dst = vt + ((size_t)blockIdx.x * 64 + d) * 1024 + kt + kc * 16;
  *(uint4*)dst = o.u[0];
  *(uint4*)(dst + 8) = o.u[1];
}

// ---------- flash attention: block-shared LDS staging + 2-phase pipeline ----------
__global__ __launch_bounds__(256, 3) void attn_kernel(const u16t* __restrict__ qkv,
                                                      const u16t* __restrict__ vt,
                                                      u16t* __restrict__ ctx) {
  __shared__ __align__(16) u16t Ks[2][64 * 64];
  __shared__ __align__(16) u16t Vs[2][64 * 64];
  __shared__ __align__(16) u16t Plds[4][32 * 72];
  int tid = threadIdx.x;
  int wave = tid >> 6, lane = tid & 63;
  int q = lane & 15, g = lane >> 4;

  int bid = blockIdx.x;
  int xcd = bid & 7, j = bid >> 3;
  int head = xcd + 8 * (j >> 3);
  int qt = (j & 7) * 128 + wave * 32;
  int b = head / 12, h = head % 12;

  const u16t* base = qkv + (size_t)b * 1024 * 2304 + h * 64;
  const u16t* kbase = base + 768;
  const u16t* vtb = vt + (size_t)head * 64 * 1024;

  short8 qf[2][2];
#pragma unroll
  for (int hf = 0; hf < 2; hf++)
#pragma unroll
    for (int hh = 0; hh < 2; hh++)
      qf[hf][hh] = *(const short8*)(base + (size_t)(qt + hf * 16 + q) * 2304 + hh * 32 + g * 8);

  int lr = lane >> 3, lc = lane & 7;
  const u16t* ksrc = kbase + (size_t)lr * 2304 + (size_t)((lc ^ lr) * 8);
  const u16t* vsrc = vtb + (size_t)lr * 1024 + (size_t)((lc ^ lr) * 8);
  int c0 = wave * 2, c1 = wave * 2 + 1;

  auto stage = [&](int kt, int buf) {
    gload_lds16(ksrc + (size_t)(kt + c0 * 8) * 2304, (void*)(Ks[buf] + c0 * 512));
    gload_lds16(ksrc + (size_t)(kt + c1 * 8) * 2304, (void*)(Ks[buf] + c1 * 512));
    gload_lds16(vsrc + (size_t)(c0 * 8) * 1024 + kt, (void*)(Vs[buf] + c0 * 512));
    gload_lds16(vsrc + (size_t)(c1 * 8) * 1024 + kt, (void*)(Vs[buf] + c1 * 512));
  };

  float mA = -1e30f, mB = -1e30f, lA = 0.f, lB = 0.f;
  f32x4 oA[4] = {}, oB[4] = {};
  u16t* Pw = Plds[wave];

  stage(0, 0);
  __syncthreads();

  for (int t = 0; t < 16; ++t) {
    int buf = t & 1;
    if (t < 15) stage((t + 1) * 64, buf ^ 1);

    const u16t* Kb = Ks[buf];
    const u16t* Vb = Vs[buf];

    f32x4 sA[4] = {}, sB[4] = {};
    __builtin_amdgcn_s_setprio(1);
#pragma unroll
    for (int n = 0; n < 4; n++) {
      int row = n * 16 + q;
      short8 k0 = *(const short8*)(Kb + row * 64 + ((g ^ (q & 7)) * 8));
      short8 k1 = *(const short8*)(Kb + row * 64 + (((4 + g) ^ (q & 7)) * 8));
      sA[n] = __builtin_amdgcn_mfma_f32_16x16x32_bf16(k0, qf[0][0], sA[n], 0, 0, 0);
      sA[n] = __builtin_amdgcn_mfma_f32_16x16x32_bf16(k1, qf[0][1], sA[n], 0, 0, 0);
      sB[n] = __builtin_amdgcn_mfma_f32_16x16x32_bf16(k0, qf[1][0], sB[n], 0, 0, 0);
      sB[n] = __builtin_amdgcn_mfma_f32_16x16x32_bf16(k1, qf[1][1], sB[n], 0, 0, 0);
    }
    __builtin_amdgcn_s_setprio(0);

    float alphaA, alphaB;
    {
      float t0 = fmaxf(fmaxf(sA[0][0], sA[0][1]), fmaxf(sA[0][2], sA[0][3]));
      float t1 = fmaxf(fmaxf(sA[1][0], sA[1][1]), fmaxf(sA[1][2], sA[1][3]));
      float t2 = fmaxf(fmaxf(sA[2][0], sA[2][1]), fmaxf(sA[2][2], sA[2][3]));
      float t3 = fmaxf(fmaxf(sA[3][0], sA[3][1]), fmaxf(sA[3][2], sA[3][3]));
      float tm = fmaxf(fmaxf(t0, t1), fmaxf(t2, t3));
      tm = fmaxf(tm, __shfl_xor(tm, 16, 64));
      tm = fmaxf(tm, __shfl_xor(tm, 32, 64));
      float mnew = fmaxf(mA, tm);
      alphaA = __expf((mA - mnew) * 0.125f);
      mA = mnew;
#pragma unroll
      for (int n = 0; n < 4; n++)
#pragma unroll
        for (int i = 0; i < 4; i++) sA[n][i] = __expf((sA[n][i] - mnew) * 0.125f);
      float r0 = (sA[0][0] + sA[0][1]) + (sA[0][2] + sA[0][3]);
      float r1 = (sA[1][0] + sA[1][1]) + (sA[1][2] + sA[1][3]);
      float r2 = (sA[2][0] + sA[2][1]) + (sA[2][2] + sA[2][3]);
      float r3 = (sA[3][0] + sA[3][1]) + (sA[3][2] + sA[3][3]);
      float rs = (r0 + r1) + (r2 + r3);
      rs += __shfl_xor(rs, 16, 64);
      rs += __shfl_xor(rs, 32, 64);
      lA = lA * alphaA + rs;
#pragma unroll
      for (int n = 0; n < 4; n++) {
        uint32_t w0 = cvtpk(sA[n][0], sA[n][1]);
        uint32_t w1 = cvtpk(sA[n][2], sA[n][3]);
        *(uint2*)(Pw + q * 72 + n * 16 + g * 4) = make_uint2(w0, w1);
      }
    }
    {
      float t0 = fmaxf(fmaxf(sB[0][0], sB[0][1]), fmaxf(sB[0][2], sB[0][3]));
      float t1 = fmaxf(fmaxf(sB[1][0], sB[1][1]), fmaxf(sB[1][2], sB[1][3]));
      float t2 = fmaxf(fmaxf(sB[2][0], sB[2][1]), fmaxf(sB[2][2], sB[2][3]));
      float t3 = fmaxf(fmaxf(sB[3][0], sB[3][1]), fmaxf(sB[3][2], sB[3][3]));
      float tm = fmaxf(fmaxf(t0, t1), fmaxf(t2, t3));
      tm = fmaxf(tm, __shfl_xor(tm, 16, 64));
      tm = fmaxf(tm, __shfl_xor(tm, 32, 64));
      float mnew = fmaxf(mB, tm);
      alphaB = __expf((mB - mnew) * 0.125f);
      mB = mnew;
#pragma unroll
      for (int n = 0; n < 4; n++)
#pragma unroll
        for (int i = 0; i < 4; i++) sB[n][i] = __expf((sB[n][i] - mnew) * 0.125f);
      float r0 = (sB[0][0] + sB[0][1]) + (sB[0][2] + sB[0][3]);
      float r1 = (sB[1][0] + sB[1][1]) + (sB[1][2] + sB[1][3]);
      float r2 = (sB[2][0] + sB[2][1]) + (sB[2][2] + sB[2][3]);
      float r3 = (sB[3][0] + sB[3][1]) + (sB[3][2] + sB[3][3]);
      float rs = (r0 + r1) + (r2 + r3);
      rs += __shfl_xor(rs, 16, 64);
      rs += __shfl_xor(rs, 32, 64);
      lB = lB * alphaB + rs;
#pragma unroll
      for (int n = 0; n < 4; n++) {
        uint32_t w0 = cvtpk(sB[n][0], sB[n][1]);
        uint32_t w1 = cvtpk(sB[n][2], sB[n][3]);
        *(uint2*)(Pw + (16 + q) * 72 + n * 16 + g * 4) = make_uint2(w0, w1);
      }
    }

#pragma unroll
    for (int n = 0; n < 4; n++)
#pragma unroll
      for (int i = 0; i < 4; i++) {
        oA[n][i] *= alphaA;
        oB[n][i] *= alphaB;
      }

    short8 pA[2], pB[2];
#pragma unroll
    for (int hh = 0; hh < 2; hh++) {
      pA[hh] = *(const short8*)(Pw + q * 72 + hh * 32 + g * 8);
      pB[hh] = *(const short8*)(Pw + (16 + q) * 72 + hh * 32 + g * 8);
    }
    __builtin_amdgcn_s_setprio(1);
#pragma unroll
    for (int n = 0; n < 4; n++) {
      int row = n * 16 + q;
      short8 v0 = *(const short8*)(Vb + row * 64 + ((g ^ (q & 7)) * 8));
      short8 v1 = *(const short8*)(Vb + row * 64 + (((4 + g) ^ (q & 7)) * 8));
      oA[n] = __builtin_amdgcn_mfma_f32_16x16x32_bf16(v0, pA[0], oA[n], 0, 0, 0);
      oA[n] = __builtin_amdgcn_mfma_f32_16x16x32_bf16(v1, pA[1], oA[n], 0, 0, 0);
      oB[n] = __builtin_amdgcn_mfma_f32_16x16x32_bf16(v0, pB[0], oB[n], 0, 0, 0);
      oB[n] = __builtin_amdgcn_mfma_f32_16x16x32_bf16(v1, pB[1], oB[n], 0, 0, 0);
    }
    __builtin_amdgcn_s_setprio(0);

    __syncthreads();
  }

  float invA = 1.f / lA, invB = 1.f / lB;
  u16t* crowA = ctx + (size_t)(b * 1024 + qt + q) * 768 + h * 64;
  u16t* crowB = ctx + (size_t)(b * 1024 + qt + 16 + q) * 768 + h * 64;
#pragma unroll
  for (int n = 0; n < 4; n++) {
    uint32_t a0 = (uint32_t)f2bf(oA[n][0] * invA) | ((uint32_t)f2bf(oA[n][1] * invA) << 16);
    uint32_t a1 = (uint32_t)f2bf(oA[n][2] * invA) | ((uint32_t)f2bf(oA[n][3] * invA) << 16);
    *(uint32_t*)(crowA + n * 16 + g * 4) = a0;
    *(uint32_t*)(crowA + n * 16 + g * 4 + 2) = a1;
    uint32_t b0 = (uint32_t)f2bf(oB[n][0] * invB) | ((uint32_t)f2bf(oB[n][1] * invB) << 16);
    uint32_t b1 = (uint32_t)f2bf(oB[n][2] * invB) | ((uint32_t)f2bf(oB[n][3] * invB) << 16);
    *(uint32_t*)(crowB + n * 16 + g * 4) = b0;
    *(uint32_t*)(crowB + n * 16 + g * 4 + 2) = b1;
  }
}

// ---------- launch ----------
extern "C" void kernel_launch(void* const* d_in, const int* in_sizes, int n_in,
                              void* d_out, int out_size, void* d_ws, size_t ws_size,
                              hipStream_t stream) {
  const float* x      = (const float*)d_in[0];
  const float* ln1_g  = (const float*)d_in[1];
  const float* ln1_b  = (const float*)d_in[2];
  const float* qkv_w  = (const float*)d_in[3];
  const float* proj_w = (const float*)d_in[4];
  const float* proj_b = (const float*)d_in[5];
  const float* ln2_g  = (const float*)d_in[6];
  const float* ln2_b  = (const float*)d_in[7];
  const float* fc1_w  = (const float*)d_in[8];
  const float* fc1_b  = (const float*)d_in[9];
  const float* fc2_w  = (const float*)d_in[10];
  const float* fc2_b  = (const float*)d_in[11];

  char* ws = (char*)d_ws;
  u16t* h1   = (u16t*)(ws + 0);           // 8192x768 bf16 (ln1 out; REUSED as vt; then ln2 out)
  u16t* qkvb = (u16t*)(ws + 12582912);    // 8192x2304 bf16
  u16t* ctx  = (u16t*)(ws + 50331648);    // 8192x768 bf16
  float* x2  = (float*)(ws + 62914560);   // 8192x768 f32
  u16t* hid  = (u16t*)(ws + 88080384);    // 8192x3072 bf16
  u16t* wq   = (u16t*)(ws + 138412032);   // 2304x768 bf16
  u16t* wp   = (u16t*)(ws + 141950976);   // 768x768 bf16
  u16t* w1   = (u16t*)(ws + 143130624);   // 3072x768 bf16
  u16t* w2   = (u16t*)(ws + 147849216);   // 768x3072 bf16
  u16t* vtb  = h1;                        // 96x64x1024 bf16, lifetime-disjoint
  float* out = (float*)d_out;

  cvt_bf16_kernel<<<864, 256, 0, stream>>>(qkv_w, wq, 221184);
  cvt_bf16_kernel<<<288, 256, 0, stream>>>(proj_w, wp, 73728);
  cvt_bf16_kernel<<<1152, 256, 0, stream>>>(fc1_w, w1, 294912);
  cvt_bf16_kernel<<<1152, 256, 0, stream>>>(fc2_w, w2, 294912);

  ln_kernel<<<8192, 256, 0, stream>>>(x, ln1_g, ln1_b, h1);
  gemm_bt<0, 128, 2><<<dim3(18, 64), 256, 0, stream>>>(h1, wq, qkvb, nullptr, nullptr, 8192, 2304, 768);
  vtrans_kernel<<<dim3(96, 16), 256, 0, stream>>>(qkvb, vtb);
  attn_kernel<<<768, 256, 0, stream>>>(qkvb, vtb, ctx);
  gemm_bt<1, 64, 3><<<dim3(6, 128), 256, 0, stream>>>(ctx, wp, x2, proj_b, x, 8192, 768, 768);
  ln_kernel<<<8192, 256, 0, stream>>>(x2, ln2_g, ln2_b, h1);
  gemm_bt<2, 128, 2><<<dim3(24, 64), 256, 0, stream>>>(h1, w1, hid, fc1_b, nullptr, 8192, 3072, 768);
  gemm_bt<1, 64, 3><<<dim3(6, 128), 256, 0, stream>>>(hid, w2, out, fc2_b, x2, 8192, 768, 3072);
}